// Round 10
// baseline (265.651 us; speedup 1.0000x reference)
//
#include <hip/hip_runtime.h>

#define N_NODES   100000
#define N_EDGES   1600000
#define NFEAT     128
#define NGRAPHS   2048
#define CBSHIFT   7                        // 128 nodes per coarse bucket
#define BSZ       128                      // bucket size
#define NCB       ((N_NODES + BSZ - 1) / BSZ)         // 782
#define N_META    (NCB * BSZ)              // 100096 rank-major meta slots (96 holes)
#define CAP       2432                     // fixed bucket capacity (mean 2046, +8.5 sigma)
#define P1_EPB    4096                     // edges per p1 block
#define P1_BLOCKS ((N_EDGES + P1_EPB - 1) / P1_EPB)   // 391
#define GEMM_BLOCKS 782
#define G1_BLOCKS 2048
#define G2_BLOCKS ((4 * N_META + 255) / 256)          // 1564
#define ZCNT      (NGRAPHS + NCB)                     // gsum|bcur = 2830
#define ZB        ((ZCNT + 255) / 256)                // 12
#define MISC_BLOCKS (17 + ZB + 8)                     // 37

typedef __attribute__((ext_vector_type(8))) short short8;
typedef __attribute__((ext_vector_type(4))) float f32x4;

// RNE float -> bf16 (finite inputs)
__device__ __forceinline__ unsigned short f2bf(float f) {
    unsigned int u = __float_as_uint(f);
    u += 0x7FFFu + ((u >> 16) & 1u);
    return (unsigned short)(u >> 16);
}

// acc[k] += s * bf16[k]  (8 bf16 packed in uint4)
__device__ __forceinline__ void acc8s(float* acc, uint4 v, float s) {
    acc[0] = fmaf(s, __uint_as_float(v.x << 16), acc[0]);
    acc[1] = fmaf(s, __uint_as_float(v.x & 0xFFFF0000u), acc[1]);
    acc[2] = fmaf(s, __uint_as_float(v.y << 16), acc[2]);
    acc[3] = fmaf(s, __uint_as_float(v.y & 0xFFFF0000u), acc[3]);
    acc[4] = fmaf(s, __uint_as_float(v.z << 16), acc[4]);
    acc[5] = fmaf(s, __uint_as_float(v.z & 0xFFFF0000u), acc[5]);
    acc[6] = fmaf(s, __uint_as_float(v.w << 16), acc[6]);
    acc[7] = fmaf(s, __uint_as_float(v.w & 0xFFFF0000u), acc[7]);
}

// ---------------- pure GEMM: C[r, slot t] = bf16((X @ W1)[r, feat 16*(t%8)+t/8]) ----------------
// feature-permuted table layout: lane m16's 16B chunk (slots 8*m16..8*m16+7) holds
// feats {m16, m16+16, ..., m16+112} -> single short8 store per fragment (8x fewer stores)
__global__ __launch_bounds__(256) void k_gemm(const float* __restrict__ X,
                                              const unsigned short* __restrict__ WT,
                                              unsigned short* __restrict__ C) {
    const int tid  = threadIdx.x;
    const int R0   = blockIdx.x * 128;
    const int wv   = tid >> 6;
    const int lane = tid & 63;
    const int m16  = lane & 15;
    const int quad = lane >> 4;
    const int r0 = R0 + wv * 32 + m16;
    const int r1 = r0 + 16;
    const bool ok0 = r0 < N_NODES, ok1 = r1 < N_NODES;

    f32x4 acc[2][8] = {};
    #pragma unroll
    for (int ks = 0; ks < 4; ++ks) {
        const int k0 = ks * 32 + quad * 8;
        short8 a0 = {}, a1 = {};
        if (ok0) {
            float4 f0 = *(const float4*)(X + (size_t)r0 * NFEAT + k0);
            float4 f1 = *(const float4*)(X + (size_t)r0 * NFEAT + k0 + 4);
            a0[0] = (short)f2bf(f0.x); a0[1] = (short)f2bf(f0.y);
            a0[2] = (short)f2bf(f0.z); a0[3] = (short)f2bf(f0.w);
            a0[4] = (short)f2bf(f1.x); a0[5] = (short)f2bf(f1.y);
            a0[6] = (short)f2bf(f1.z); a0[7] = (short)f2bf(f1.w);
        }
        if (ok1) {
            float4 f0 = *(const float4*)(X + (size_t)r1 * NFEAT + k0);
            float4 f1 = *(const float4*)(X + (size_t)r1 * NFEAT + k0 + 4);
            a1[0] = (short)f2bf(f0.x); a1[1] = (short)f2bf(f0.y);
            a1[2] = (short)f2bf(f0.z); a1[3] = (short)f2bf(f0.w);
            a1[4] = (short)f2bf(f1.x); a1[5] = (short)f2bf(f1.y);
            a1[6] = (short)f2bf(f1.z); a1[7] = (short)f2bf(f1.w);
        }
        #pragma unroll
        for (int ct = 0; ct < 8; ++ct) {
            short8 bb = *(const short8*)(WT + (ct * 16 + m16) * 128 + k0);
            acc[0][ct] = __builtin_amdgcn_mfma_f32_16x16x32_bf16(a0, bb, acc[0][ct], 0, 0, 0);
            acc[1][ct] = __builtin_amdgcn_mfma_f32_16x16x32_bf16(a1, bb, acc[1][ct], 0, 0, 0);
        }
    }
    #pragma unroll
    for (int t2 = 0; t2 < 2; ++t2) {
        int rbase = R0 + wv * 32 + t2 * 16 + quad * 4;
        #pragma unroll
        for (int reg = 0; reg < 4; ++reg) {
            int gr = rbase + reg;
            if (gr < N_NODES) {
                short8 v;
                #pragma unroll
                for (int ct = 0; ct < 8; ++ct)
                    v[ct] = (short)f2bf(acc[t2][ct][reg]);
                *(short8*)(C + (size_t)gr * NFEAT + m16 * 8) = v;
            }
        }
    }
}

// ---------------- multi-role setup: 0-15 WT1, 16 w2l, zeroing, graph counts ----------------
__global__ __launch_bounds__(256) void k_misc(const float* __restrict__ W1,
                                              unsigned short* __restrict__ WT1,
                                              const float* __restrict__ W2,
                                              const float* __restrict__ Wlin,
                                              const float* __restrict__ b2,
                                              const float* __restrict__ blin,
                                              float* __restrict__ w2l,
                                              int* __restrict__ zeros,
                                              const int* __restrict__ batch,
                                              float* __restrict__ cntf) {
    const int blk = blockIdx.x;
    const int t = threadIdx.x;
    if (blk < 16) {
        int base = blk * 1024 + t * 4;
        #pragma unroll
        for (int q = 0; q < 4; ++q) {
            int i = base + q;
            int n = i >> 7, k = i & 127;
            WT1[i] = f2bf(W1[k * 128 + n]);
        }
    } else if (blk == 16) {
        __shared__ float s[256];
        int i = t >> 1, half = t & 1;
        float ps = 0.f;
        for (int j = half * 64; j < half * 64 + 64; ++j)
            ps += W2[i * 128 + j] * Wlin[j];
        s[t] = ps;
        __syncthreads();
        if (!half) w2l[i] = s[t] + s[t + 1];
        __syncthreads();
        float pc = (t < 128) ? b2[t] * Wlin[t] : 0.f;
        s[t] = pc;
        __syncthreads();
        for (int off = 128; off > 0; off >>= 1) {
            if (t < off) s[t] += s[t + off];
            __syncthreads();
        }
        if (t == 0) w2l[128] = s[0] + blin[0];
    } else if (blk < 17 + ZB) {
        int i = (blk - 17) * 256 + t;
        if (i < ZCNT) zeros[i] = 0;
    } else {
        // graph node-counts via binary search on sorted batch
        int g = (blk - (17 + ZB)) * 256 + t;   // 8 blocks cover 2048
        int lo = 0, hi = N_NODES;
        while (lo < hi) { int m = (lo + hi) >> 1; if (batch[m] < g) lo = m + 1; else hi = m; }
        int lb = lo;
        lo = 0; hi = N_NODES;
        int g1 = g + 1;
        while (lo < hi) { int m = (lo + hi) >> 1; if (batch[m] < g1) lo = m + 1; else hi = m; }
        cntf[g] = fmaxf((float)(lo - lb), 1.0f);
    }
}

// ---------------- pass 1 (standalone): scatter into FIXED bucket regions ----------------
__global__ __launch_bounds__(256) void k_p1(const int* __restrict__ src,
                                            const int* __restrict__ dst,
                                            int* __restrict__ bcur,
                                            unsigned int* __restrict__ pairs) {
    const int b = blockIdx.x;
    __shared__ int hist[NCB], base[NCB], cur[NCB];
    const int t = threadIdx.x;
    for (int i = t; i < NCB; i += 256) { hist[i] = 0; cur[i] = 0; }
    __syncthreads();
    const int e0 = b * P1_EPB;
    const int e1 = min(e0 + P1_EPB, N_EDGES);
    for (int e = e0 + t; e < e1; e += 256)
        atomicAdd(&hist[dst[e] >> CBSHIFT], 1);
    __syncthreads();
    // staggered reservation order: spread per-bucket atomic queues
    const int off0 = (b * 89) % NCB;
    for (int k = t; k < NCB; k += 256) {
        int i = k + off0;
        if (i >= NCB) i -= NCB;
        int c = hist[i];
        base[i] = c ? (i * CAP + atomicAdd(&bcur[i], c)) : 0;
    }
    __syncthreads();
    for (int e = e0 + t; e < e1; e += 256) {
        int d = dst[e];
        int bb = d >> CBSHIFT;
        int r = atomicAdd(&cur[bb], 1);
        int idx = base[bb] + r;
        if (idx < (bb + 1) * CAP)   // overflow guard (P ~ 1e-13, keeps memory safe)
            pairs[idx] = (unsigned int)src[e] | ((unsigned int)(d & (BSZ - 1)) << 17);
    }
}

// ---------------- pass 2 (standalone): bucket sort + rank-major meta ----------------
__global__ __launch_bounds__(256) void k_p2(const unsigned int* __restrict__ pairs,
                                            const int* __restrict__ bcur,
                                            int* __restrict__ csr_src,
                                            float* __restrict__ dinv,
                                            int4* __restrict__ meta) {
    const int b = blockIdx.x;     // bucket id [0,782)
    __shared__ int hist[BSZ], sst[BSZ], cur[BSZ], s[BSZ], dh[64], dhc[64];
    const int t = threadIdx.x;
    const int beg = b * CAP;
    const int end = beg + min(bcur[b], CAP);
    if (t < BSZ) { hist[t] = 0; cur[t] = 0; }
    if (t < 64) { dh[t] = 0; dhc[t] = 0; }
    __syncthreads();
    for (int i = beg + t; i < end; i += 256)
        atomicAdd(&hist[pairs[i] >> 17], 1);
    __syncthreads();
    int v = (t < BSZ) ? hist[t] : 0;
    if (t < BSZ) s[t] = v;
    __syncthreads();
    for (int off = 1; off < BSZ; off <<= 1) {
        int x = (t >= off && t < BSZ) ? s[t - off] : 0;
        __syncthreads();
        if (t < BSZ) s[t] += x;
        __syncthreads();
    }
    if (t < BSZ) sst[t] = s[t] - v;
    __syncthreads();
    const int node = (b << CBSHIFT) + t;
    const bool valid = (t < BSZ) && (node < N_NODES);
    if (valid) {
        dinv[node] = rsqrtf((float)v + 1.0f);
        atomicAdd(&dh[63 - min(v, 63)], 1);
    }
    for (int i = beg + t; i < end; i += 256) {
        unsigned int pv = pairs[i];
        int dl = pv >> 17;
        int r = atomicAdd(&cur[dl], 1);
        csr_src[beg + sst[dl] + r] = (int)(pv & 0x1FFFFu);
    }
    __syncthreads();
    // bucket-local degree sort: 64-bin inclusive scan of dh
    if (t < 64) s[t] = dh[t];
    __syncthreads();
    for (int off = 1; off < 64; off <<= 1) {
        int x = (t >= off && t < 64) ? s[t - off] : 0;
        __syncthreads();
        if (t < 64) s[t] += x;
        __syncthreads();
    }
    if (valid) {
        int bin = 63 - min(v, 63);
        int r = atomicAdd(&dhc[bin], 1);
        int rank = s[bin] - dh[bin] + r;           // exclusive prefix + within-bin slot
        meta[(size_t)rank * NCB + b] =
            make_int4(beg + sst[t], v, __float_as_int(rsqrtf((float)v + 1.0f)), node);
    } else if (t < BSZ) {
        meta[(size_t)t * NCB + b] = make_int4(0, 0, 0, -1);
    }
}

// ---------------- gather layer 1 (per-edge dinv) + fused z projection ----------------
// static grid-stride; masked full chunks; A/B double-buffered gathers (proven 63 us)
// table is feature-permuted: acc[j] of lane p holds feat 16*j+p -> permuted b/w preload
__global__ __launch_bounds__(256) void k_gather1(const unsigned short* __restrict__ xwb,
                                                 const int* __restrict__ csr_src,
                                                 const float* __restrict__ dinv,
                                                 const float* __restrict__ b,
                                                 const float* __restrict__ w2l,
                                                 const int4* __restrict__ meta,
                                                 float* __restrict__ z) {
    const int t     = threadIdx.x;
    const int lane  = t & 63;
    const int p     = lane & 15;
    const int gbase = lane & 48;
    const int j0    = p & 7;
    const int ngroups = G1_BLOCKS * 16;
    int gid = blockIdx.x * 16 + (t >> 4);
    const uint4* tab = (const uint4*)xwb;
    float bl[8], wl[8];
    #pragma unroll
    for (int j = 0; j < 8; ++j) { bl[j] = b[16 * j + p]; wl[j] = w2l[16 * j + p]; }

    for (int nidx = gid; nidx < N_META; nidx += ngroups) {
        const int4 md = meta[nidx];
        const int node  = md.w;
        if (node < 0) continue;                  // hole slot
        const int beg   = md.x;
        const int cnt   = md.y;
        const float dvn = __int_as_float(md.z);
        float acc[8] = {};
        acc8s(acc, tab[(size_t)node * 16 + p], dvn);   // self loop
        const int nch = (cnt + 7) >> 3;
        if (nch) {
            int myA; float dvA; uint4 vA[8];
            int myB; float dvB; uint4 vB[8];
            {   // chunk 0 -> A
                bool vld = j0 < cnt;
                int jj = vld ? j0 : 0;
                int sld = csr_src[beg + jj];
                myA = vld ? sld : node;
                float dv = dinv[myA];
                dvA = vld ? dv : 0.f;
                #pragma unroll
                for (int q = 0; q < 8; ++q) {
                    int idx = __shfl(myA, gbase + q);
                    vA[q] = tab[(size_t)idx * 16 + p];
                }
            }
            int c = 0;
            for (;;) {
                const bool hb = (c + 1 < nch);
                if (hb) {
                    int j = (c + 1) * 8 + j0;
                    bool vld = j < cnt;
                    int jj = vld ? j : 0;
                    int sld = csr_src[beg + jj];
                    myB = vld ? sld : node;
                    float dv = dinv[myB];
                    dvB = vld ? dv : 0.f;
                    #pragma unroll
                    for (int q = 0; q < 8; ++q) {
                        int idx = __shfl(myB, gbase + q);
                        vB[q] = tab[(size_t)idx * 16 + p];
                    }
                }
                #pragma unroll
                for (int q = 0; q < 8; ++q) {
                    float sv = __shfl(dvA, gbase + q);
                    acc8s(acc, vA[q], sv);
                }
                ++c;
                if (!hb) break;
                const bool ha = (c + 1 < nch);
                if (ha) {
                    int j = (c + 1) * 8 + j0;
                    bool vld = j < cnt;
                    int jj = vld ? j : 0;
                    int sld = csr_src[beg + jj];
                    myA = vld ? sld : node;
                    float dv = dinv[myA];
                    dvA = vld ? dv : 0.f;
                    #pragma unroll
                    for (int q = 0; q < 8; ++q) {
                        int idx = __shfl(myA, gbase + q);
                        vA[q] = tab[(size_t)idx * 16 + p];
                    }
                }
                #pragma unroll
                for (int q = 0; q < 8; ++q) {
                    float sv = __shfl(dvB, gbase + q);
                    acc8s(acc, vB[q], sv);
                }
                ++c;
                if (!ha) break;
            }
        }
        float s = 0.f;
        #pragma unroll
        for (int j = 0; j < 8; ++j)
            s = fmaf(fmaxf(fmaf(acc[j], dvn, bl[j]), 0.f), wl[j], s);
        s += __shfl_xor(s, 1);
        s += __shfl_xor(s, 2);
        s += __shfl_xor(s, 4);
        s += __shfl_xor(s, 8);
        if (p == 0) z[node] = s * dvn;
    }
}

// ---------------- layer 2 + pool over scalars: 4 lanes per node (no fence) ----------------
__global__ __launch_bounds__(256) void k_g2(const float* __restrict__ z,
                                            const int* __restrict__ csr_src,
                                            const int4* __restrict__ meta,
                                            const int* __restrict__ batch,
                                            float* __restrict__ gsum) {
    int tid = blockIdx.x * blockDim.x + threadIdx.x;
    int nidx = tid >> 2;
    int q = tid & 3;
    if (nidx >= N_META) return;
    int4 md = meta[nidx];
    const int node = md.w;
    if (node < 0) return;                        // hole slot
    const int beg = md.x, cnt = md.y;
    const float dvn = __int_as_float(md.z);
    float a = (q == 0) ? z[node] : 0.f;
    for (int j = q; j < cnt; j += 4)
        a += z[csr_src[beg + j]];
    a += __shfl_xor(a, 1);
    a += __shfl_xor(a, 2);
    if (q == 0) atomicAdd(&gsum[batch[node]], a * dvn);
}

// ---------------- final: trivial (counts precomputed in k_misc) ----------------
__global__ void k_final(const float* __restrict__ gsum, const float* __restrict__ cntf,
                        const float* __restrict__ c2, float* __restrict__ out) {
    int g = blockIdx.x * blockDim.x + threadIdx.x;
    if (g >= NGRAPHS) return;
    out[g] = gsum[g] / cntf[g] + c2[0];
}

extern "C" void kernel_launch(void* const* d_in, const int* in_sizes, int n_in,
                              void* d_out, int out_size, void* d_ws, size_t ws_size,
                              hipStream_t stream) {
    const float* x    = (const float*)d_in[0];
    const int*   ei   = (const int*)d_in[1];
    const int*   bat  = (const int*)d_in[2];
    const float* W1   = (const float*)d_in[3];
    const float* b1   = (const float*)d_in[4];
    const float* W2   = (const float*)d_in[5];
    const float* b2   = (const float*)d_in[6];
    const float* Wlin = (const float*)d_in[7];
    const float* blin = (const float*)d_in[8];
    float* out = (float*)d_out;

    const int* src = ei;
    const int* dst = ei + N_EDGES;

    // ---- workspace layout ----
    const size_t NF = (size_t)N_NODES * NFEAT;
    unsigned short* bufA = (unsigned short*)d_ws;          // bf16 xw1 table (25.6 MB)
    float* z       = (float*)(bufA + NF);                  // [N]
    float* dinv    = z + N_NODES;                          // [N]
    // zeroed-by-misc region (contiguous): gsum | bcur
    float* gsum    = dinv + N_NODES;                       // [G]
    int* bcur      = (int*)(gsum + NGRAPHS);               // [NCB] bucket fill cursors
    float* cntf    = (float*)(bcur + NCB);                 // [G] (written by misc)
    unsigned short* WT1 = (unsigned short*)(cntf + NGRAPHS); // [16384]
    float* w2l     = (float*)(WT1 + 128 * 128);            // [132] (c2 at [128])
    unsigned int* pairs = (unsigned int*)(w2l + 132);      // [NCB*CAP] fixed regions
    int* csr_src   = (int*)(pairs + (size_t)NCB * CAP);    // [NCB*CAP] fixed regions
    int4* meta     = (int4*)(((size_t)(csr_src + (size_t)NCB * CAP) + 15) & ~(size_t)15);

    const int BS = 256;

    // 1. setup: weights, zeroing, graph counts
    k_misc<<<MISC_BLOCKS, BS, 0, stream>>>(W1, WT1, W2, Wlin, b2, blin, w2l,
                                           (int*)gsum, bat, cntf);
    // 2. pure GEMM (permuted short8 C-store)
    k_gemm<<<GEMM_BLOCKS, BS, 0, stream>>>(x, WT1, bufA);
    // 3. pass-1 scatter into fixed bucket regions (standalone)
    k_p1<<<P1_BLOCKS, BS, 0, stream>>>(src, dst, bcur, pairs);
    // 4. pass-2 bucket sort + rank-major meta (standalone)
    k_p2<<<NCB, BS, 0, stream>>>(pairs, bcur, csr_src, dinv, meta);
    // 5. layer-1 gather + fused projection to scalar z
    k_gather1<<<G1_BLOCKS, BS, 0, stream>>>(bufA, csr_src, dinv, b1, w2l, meta, z);
    // 6. layer-2 + pool over scalar z
    k_g2<<<G2_BLOCKS, BS, 0, stream>>>(z, csr_src, meta, bat, gsum);
    // 7. final (trivial)
    k_final<<<(NGRAPHS + BS - 1) / BS, BS, 0, stream>>>(gsum, cntf, w2l + 128, out);
}

// Round 11
// 243.247 us; speedup vs baseline: 1.0921x; 1.0921x over previous
//
#include <hip/hip_runtime.h>

#define N_NODES   100000
#define N_EDGES   1600000
#define NFEAT     128
#define NGRAPHS   2048
#define CBSHIFT   7                        // 128 nodes per coarse bucket
#define BSZ       128                      // bucket size
#define NCB       ((N_NODES + BSZ - 1) / BSZ)         // 782
#define N_META    (NCB * BSZ)              // 100096 rank-major meta slots (96 holes)
#define CAP       2432                     // fixed bucket capacity (mean 2046, +8.5 sigma)
#define P1_EPB    8192                     // edges per p1 block
#define P1_BLOCKS ((N_EDGES + P1_EPB - 1) / P1_EPB)   // 196
#define GEMM_HALF   391
#define G1_BLOCKS 2048
#define G2_BLOCKS ((4 * N_META + 255) / 256)          // 1564
#define ZCNT      (NGRAPHS + NCB)                     // gsum|bcur = 2830
#define ZB        ((ZCNT + 255) / 256)                // 12
#define MISC_BLOCKS (17 + ZB + 8)                     // 37

typedef __attribute__((ext_vector_type(8))) short short8;
typedef __attribute__((ext_vector_type(4))) float f32x4;

// RNE float -> bf16 (finite inputs)
__device__ __forceinline__ unsigned short f2bf(float f) {
    unsigned int u = __float_as_uint(f);
    u += 0x7FFFu + ((u >> 16) & 1u);
    return (unsigned short)(u >> 16);
}

// acc[k] += s * bf16[k]  (8 bf16 packed in uint4)
__device__ __forceinline__ void acc8s(float* acc, uint4 v, float s) {
    acc[0] = fmaf(s, __uint_as_float(v.x << 16), acc[0]);
    acc[1] = fmaf(s, __uint_as_float(v.x & 0xFFFF0000u), acc[1]);
    acc[2] = fmaf(s, __uint_as_float(v.y << 16), acc[2]);
    acc[3] = fmaf(s, __uint_as_float(v.y & 0xFFFF0000u), acc[3]);
    acc[4] = fmaf(s, __uint_as_float(v.z << 16), acc[4]);
    acc[5] = fmaf(s, __uint_as_float(v.z & 0xFFFF0000u), acc[5]);
    acc[6] = fmaf(s, __uint_as_float(v.w << 16), acc[6]);
    acc[7] = fmaf(s, __uint_as_float(v.w & 0xFFFF0000u), acc[7]);
}

// ---------------- GEMM tile with feature-permuted short8 C-store ----------------
// C[r, slot 8*m16+ct] = bf16((X@W1)[r, feat ct*16+m16]) -> one 16B store per fragment
__device__ __forceinline__ void gemm_tile(const float* __restrict__ X,
                                          const unsigned short* __restrict__ WT,
                                          unsigned short* __restrict__ C,
                                          int gblk, int tid) {
    const int R0   = gblk * 128;
    const int wv   = tid >> 6;
    const int lane = tid & 63;
    const int m16  = lane & 15;
    const int quad = lane >> 4;
    const int r0 = R0 + wv * 32 + m16;
    const int r1 = r0 + 16;
    const bool ok0 = r0 < N_NODES, ok1 = r1 < N_NODES;

    f32x4 acc[2][8] = {};
    #pragma unroll
    for (int ks = 0; ks < 4; ++ks) {
        const int k0 = ks * 32 + quad * 8;
        short8 a0 = {}, a1 = {};
        if (ok0) {
            float4 f0 = *(const float4*)(X + (size_t)r0 * NFEAT + k0);
            float4 f1 = *(const float4*)(X + (size_t)r0 * NFEAT + k0 + 4);
            a0[0] = (short)f2bf(f0.x); a0[1] = (short)f2bf(f0.y);
            a0[2] = (short)f2bf(f0.z); a0[3] = (short)f2bf(f0.w);
            a0[4] = (short)f2bf(f1.x); a0[5] = (short)f2bf(f1.y);
            a0[6] = (short)f2bf(f1.z); a0[7] = (short)f2bf(f1.w);
        }
        if (ok1) {
            float4 f0 = *(const float4*)(X + (size_t)r1 * NFEAT + k0);
            float4 f1 = *(const float4*)(X + (size_t)r1 * NFEAT + k0 + 4);
            a1[0] = (short)f2bf(f0.x); a1[1] = (short)f2bf(f0.y);
            a1[2] = (short)f2bf(f0.z); a1[3] = (short)f2bf(f0.w);
            a1[4] = (short)f2bf(f1.x); a1[5] = (short)f2bf(f1.y);
            a1[6] = (short)f2bf(f1.z); a1[7] = (short)f2bf(f1.w);
        }
        #pragma unroll
        for (int ct = 0; ct < 8; ++ct) {
            short8 bb = *(const short8*)(WT + (ct * 16 + m16) * 128 + k0);
            acc[0][ct] = __builtin_amdgcn_mfma_f32_16x16x32_bf16(a0, bb, acc[0][ct], 0, 0, 0);
            acc[1][ct] = __builtin_amdgcn_mfma_f32_16x16x32_bf16(a1, bb, acc[1][ct], 0, 0, 0);
        }
    }
    #pragma unroll
    for (int t2 = 0; t2 < 2; ++t2) {
        int rbase = R0 + wv * 32 + t2 * 16 + quad * 4;
        #pragma unroll
        for (int reg = 0; reg < 4; ++reg) {
            int gr = rbase + reg;
            if (gr < N_NODES) {
                short8 v;
                #pragma unroll
                for (int ct = 0; ct < 8; ++ct)
                    v[ct] = (short)f2bf(acc[t2][ct][reg]);
                *(short8*)(C + (size_t)gr * NFEAT + m16 * 8) = v;
            }
        }
    }
}

// ---------------- multi-role setup: 0-15 WT1, 16 w2l, zeroing, graph counts ----------------
__global__ __launch_bounds__(256) void k_misc(const float* __restrict__ W1,
                                              unsigned short* __restrict__ WT1,
                                              const float* __restrict__ W2,
                                              const float* __restrict__ Wlin,
                                              const float* __restrict__ b2,
                                              const float* __restrict__ blin,
                                              float* __restrict__ w2l,
                                              int* __restrict__ zeros,
                                              const int* __restrict__ batch,
                                              float* __restrict__ cntf) {
    const int blk = blockIdx.x;
    const int t = threadIdx.x;
    if (blk < 16) {
        int base = blk * 1024 + t * 4;
        #pragma unroll
        for (int q = 0; q < 4; ++q) {
            int i = base + q;
            int n = i >> 7, k = i & 127;
            WT1[i] = f2bf(W1[k * 128 + n]);
        }
    } else if (blk == 16) {
        __shared__ float s[256];
        int i = t >> 1, half = t & 1;
        float ps = 0.f;
        for (int j = half * 64; j < half * 64 + 64; ++j)
            ps += W2[i * 128 + j] * Wlin[j];
        s[t] = ps;
        __syncthreads();
        if (!half) w2l[i] = s[t] + s[t + 1];
        __syncthreads();
        float pc = (t < 128) ? b2[t] * Wlin[t] : 0.f;
        s[t] = pc;
        __syncthreads();
        for (int off = 128; off > 0; off >>= 1) {
            if (t < off) s[t] += s[t + off];
            __syncthreads();
        }
        if (t == 0) w2l[128] = s[0] + blin[0];
    } else if (blk < 17 + ZB) {
        int i = (blk - 17) * 256 + t;
        if (i < ZCNT) zeros[i] = 0;
    } else {
        // graph node-counts via binary search on sorted batch
        int g = (blk - (17 + ZB)) * 256 + t;   // 8 blocks cover 2048
        int lo = 0, hi = N_NODES;
        while (lo < hi) { int m = (lo + hi) >> 1; if (batch[m] < g) lo = m + 1; else hi = m; }
        int lb = lo;
        lo = 0; hi = N_NODES;
        int g1 = g + 1;
        while (lo < hi) { int m = (lo + hi) >> 1; if (batch[m] < g1) lo = m + 1; else hi = m; }
        cntf[g] = fmaxf((float)(lo - lb), 1.0f);
    }
}

// ---------------- launch 2: GEMM half A || pass-1 scatter into FIXED bucket regions ----------------
__global__ __launch_bounds__(256) void k_gA_p1(const float* __restrict__ X,
                                               const unsigned short* __restrict__ WT,
                                               unsigned short* __restrict__ C,
                                               const int* __restrict__ src,
                                               const int* __restrict__ dst,
                                               int* __restrict__ bcur,
                                               unsigned int* __restrict__ pairs) {
    if (blockIdx.x < GEMM_HALF) {
        gemm_tile(X, WT, C, blockIdx.x, threadIdx.x);
        return;
    }
    const int b = blockIdx.x - GEMM_HALF;     // p1 block id [0,196)
    __shared__ int hist[NCB], base[NCB], cur[NCB];
    const int t = threadIdx.x;
    for (int i = t; i < NCB; i += 256) { hist[i] = 0; cur[i] = 0; }
    __syncthreads();
    const int e0 = b * P1_EPB;
    const int e1 = min(e0 + P1_EPB, N_EDGES);
    for (int e = e0 + t; e < e1; e += 256)
        atomicAdd(&hist[dst[e] >> CBSHIFT], 1);
    __syncthreads();
    // staggered reservation order: spread per-bucket atomic queues
    const int off0 = (b * 89) % NCB;
    for (int k = t; k < NCB; k += 256) {
        int i = k + off0;
        if (i >= NCB) i -= NCB;
        int c = hist[i];
        base[i] = c ? (i * CAP + atomicAdd(&bcur[i], c)) : 0;
    }
    __syncthreads();
    for (int e = e0 + t; e < e1; e += 256) {
        int d = dst[e];
        int bb = d >> CBSHIFT;
        int r = atomicAdd(&cur[bb], 1);
        int idx = base[bb] + r;
        if (idx < (bb + 1) * CAP)   // overflow guard (P ~ 1e-13, keeps memory safe)
            pairs[idx] = (unsigned int)src[e] | ((unsigned int)(d & (BSZ - 1)) << 17);
    }
}

// ---------------- launch 3: GEMM half B || pass-2 bucket sort + rank-major meta ----------------
__global__ __launch_bounds__(256) void k_gB_p2(const float* __restrict__ X,
                                               const unsigned short* __restrict__ WT,
                                               unsigned short* __restrict__ C,
                                               const unsigned int* __restrict__ pairs,
                                               const int* __restrict__ bcur,
                                               int* __restrict__ csr_src,
                                               float* __restrict__ dinv,
                                               int4* __restrict__ meta) {
    if (blockIdx.x < GEMM_HALF) {
        gemm_tile(X, WT, C, blockIdx.x + GEMM_HALF, threadIdx.x);
        return;
    }
    const int b = blockIdx.x - GEMM_HALF;     // bucket id [0,782)
    __shared__ int hist[BSZ], sst[BSZ], cur[BSZ], s[BSZ], dh[64], dhc[64];
    const int t = threadIdx.x;
    const int beg = b * CAP;
    const int end = beg + min(bcur[b], CAP);
    if (t < BSZ) { hist[t] = 0; cur[t] = 0; }
    if (t < 64) { dh[t] = 0; dhc[t] = 0; }
    __syncthreads();
    for (int i = beg + t; i < end; i += 256)
        atomicAdd(&hist[pairs[i] >> 17], 1);
    __syncthreads();
    int v = (t < BSZ) ? hist[t] : 0;
    if (t < BSZ) s[t] = v;
    __syncthreads();
    for (int off = 1; off < BSZ; off <<= 1) {
        int x = (t >= off && t < BSZ) ? s[t - off] : 0;
        __syncthreads();
        if (t < BSZ) s[t] += x;
        __syncthreads();
    }
    if (t < BSZ) sst[t] = s[t] - v;
    __syncthreads();
    const int node = (b << CBSHIFT) + t;
    const bool valid = (t < BSZ) && (node < N_NODES);
    if (valid) {
        dinv[node] = rsqrtf((float)v + 1.0f);
        atomicAdd(&dh[63 - min(v, 63)], 1);
    }
    for (int i = beg + t; i < end; i += 256) {
        unsigned int pv = pairs[i];
        int dl = pv >> 17;
        int r = atomicAdd(&cur[dl], 1);
        csr_src[beg + sst[dl] + r] = (int)(pv & 0x1FFFFu);
    }
    __syncthreads();
    // bucket-local degree sort: 64-bin inclusive scan of dh
    if (t < 64) s[t] = dh[t];
    __syncthreads();
    for (int off = 1; off < 64; off <<= 1) {
        int x = (t >= off && t < 64) ? s[t - off] : 0;
        __syncthreads();
        if (t < 64) s[t] += x;
        __syncthreads();
    }
    if (valid) {
        int bin = 63 - min(v, 63);
        int r = atomicAdd(&dhc[bin], 1);
        int rank = s[bin] - dh[bin] + r;           // exclusive prefix + within-bin slot
        meta[(size_t)rank * NCB + b] =
            make_int4(beg + sst[t], v, __float_as_int(rsqrtf((float)v + 1.0f)), node);
    } else if (t < BSZ) {
        meta[(size_t)t * NCB + b] = make_int4(0, 0, 0, -1);
    }
}

// ---------------- gather layer 1 (per-edge dinv) + fused z projection ----------------
// static grid-stride; masked full chunks; A/B double-buffered gathers (proven 63 us)
// table is feature-permuted: acc[j] of lane p holds feat 16*j+p -> permuted b/w preload
__global__ __launch_bounds__(256) void k_gather1(const unsigned short* __restrict__ xwb,
                                                 const int* __restrict__ csr_src,
                                                 const float* __restrict__ dinv,
                                                 const float* __restrict__ b,
                                                 const float* __restrict__ w2l,
                                                 const int4* __restrict__ meta,
                                                 float* __restrict__ z) {
    const int t     = threadIdx.x;
    const int lane  = t & 63;
    const int p     = lane & 15;
    const int gbase = lane & 48;
    const int j0    = p & 7;
    const int ngroups = G1_BLOCKS * 16;
    int gid = blockIdx.x * 16 + (t >> 4);
    const uint4* tab = (const uint4*)xwb;
    float bl[8], wl[8];
    #pragma unroll
    for (int j = 0; j < 8; ++j) { bl[j] = b[16 * j + p]; wl[j] = w2l[16 * j + p]; }

    for (int nidx = gid; nidx < N_META; nidx += ngroups) {
        const int4 md = meta[nidx];
        const int node  = md.w;
        if (node < 0) continue;                  // hole slot
        const int beg   = md.x;
        const int cnt   = md.y;
        const float dvn = __int_as_float(md.z);
        float acc[8] = {};
        acc8s(acc, tab[(size_t)node * 16 + p], dvn);   // self loop
        const int nch = (cnt + 7) >> 3;
        if (nch) {
            int myA; float dvA; uint4 vA[8];
            int myB; float dvB; uint4 vB[8];
            {   // chunk 0 -> A
                bool vld = j0 < cnt;
                int jj = vld ? j0 : 0;
                int sld = csr_src[beg + jj];
                myA = vld ? sld : node;
                float dv = dinv[myA];
                dvA = vld ? dv : 0.f;
                #pragma unroll
                for (int q = 0; q < 8; ++q) {
                    int idx = __shfl(myA, gbase + q);
                    vA[q] = tab[(size_t)idx * 16 + p];
                }
            }
            int c = 0;
            for (;;) {
                const bool hb = (c + 1 < nch);
                if (hb) {
                    int j = (c + 1) * 8 + j0;
                    bool vld = j < cnt;
                    int jj = vld ? j : 0;
                    int sld = csr_src[beg + jj];
                    myB = vld ? sld : node;
                    float dv = dinv[myB];
                    dvB = vld ? dv : 0.f;
                    #pragma unroll
                    for (int q = 0; q < 8; ++q) {
                        int idx = __shfl(myB, gbase + q);
                        vB[q] = tab[(size_t)idx * 16 + p];
                    }
                }
                #pragma unroll
                for (int q = 0; q < 8; ++q) {
                    float sv = __shfl(dvA, gbase + q);
                    acc8s(acc, vA[q], sv);
                }
                ++c;
                if (!hb) break;
                const bool ha = (c + 1 < nch);
                if (ha) {
                    int j = (c + 1) * 8 + j0;
                    bool vld = j < cnt;
                    int jj = vld ? j : 0;
                    int sld = csr_src[beg + jj];
                    myA = vld ? sld : node;
                    float dv = dinv[myA];
                    dvA = vld ? dv : 0.f;
                    #pragma unroll
                    for (int q = 0; q < 8; ++q) {
                        int idx = __shfl(myA, gbase + q);
                        vA[q] = tab[(size_t)idx * 16 + p];
                    }
                }
                #pragma unroll
                for (int q = 0; q < 8; ++q) {
                    float sv = __shfl(dvB, gbase + q);
                    acc8s(acc, vB[q], sv);
                }
                ++c;
                if (!ha) break;
            }
        }
        float s = 0.f;
        #pragma unroll
        for (int j = 0; j < 8; ++j)
            s = fmaf(fmaxf(fmaf(acc[j], dvn, bl[j]), 0.f), wl[j], s);
        s += __shfl_xor(s, 1);
        s += __shfl_xor(s, 2);
        s += __shfl_xor(s, 4);
        s += __shfl_xor(s, 8);
        if (p == 0) z[node] = s * dvn;
    }
}

// ---------------- layer 2 + pool over scalars: 4 lanes per node (no fence) ----------------
__global__ __launch_bounds__(256) void k_g2(const float* __restrict__ z,
                                            const int* __restrict__ csr_src,
                                            const int4* __restrict__ meta,
                                            const int* __restrict__ batch,
                                            float* __restrict__ gsum) {
    int tid = blockIdx.x * blockDim.x + threadIdx.x;
    int nidx = tid >> 2;
    int q = tid & 3;
    if (nidx >= N_META) return;
    int4 md = meta[nidx];
    const int node = md.w;
    if (node < 0) return;                        // hole slot
    const int beg = md.x, cnt = md.y;
    const float dvn = __int_as_float(md.z);
    float a = (q == 0) ? z[node] : 0.f;
    for (int j = q; j < cnt; j += 4)
        a += z[csr_src[beg + j]];
    a += __shfl_xor(a, 1);
    a += __shfl_xor(a, 2);
    if (q == 0) atomicAdd(&gsum[batch[node]], a * dvn);
}

// ---------------- final: trivial (counts precomputed in k_misc) ----------------
__global__ void k_final(const float* __restrict__ gsum, const float* __restrict__ cntf,
                        const float* __restrict__ c2, float* __restrict__ out) {
    int g = blockIdx.x * blockDim.x + threadIdx.x;
    if (g >= NGRAPHS) return;
    out[g] = gsum[g] / cntf[g] + c2[0];
}

extern "C" void kernel_launch(void* const* d_in, const int* in_sizes, int n_in,
                              void* d_out, int out_size, void* d_ws, size_t ws_size,
                              hipStream_t stream) {
    const float* x    = (const float*)d_in[0];
    const int*   ei   = (const int*)d_in[1];
    const int*   bat  = (const int*)d_in[2];
    const float* W1   = (const float*)d_in[3];
    const float* b1   = (const float*)d_in[4];
    const float* W2   = (const float*)d_in[5];
    const float* b2   = (const float*)d_in[6];
    const float* Wlin = (const float*)d_in[7];
    const float* blin = (const float*)d_in[8];
    float* out = (float*)d_out;

    const int* src = ei;
    const int* dst = ei + N_EDGES;

    // ---- workspace layout ----
    const size_t NF = (size_t)N_NODES * NFEAT;
    unsigned short* bufA = (unsigned short*)d_ws;          // bf16 xw1 table (25.6 MB)
    float* z       = (float*)(bufA + NF);                  // [N]
    float* dinv    = z + N_NODES;                          // [N]
    // zeroed-by-misc region (contiguous): gsum | bcur
    float* gsum    = dinv + N_NODES;                       // [G]
    int* bcur      = (int*)(gsum + NGRAPHS);               // [NCB] bucket fill cursors
    float* cntf    = (float*)(bcur + NCB);                 // [G] (written by misc)
    unsigned short* WT1 = (unsigned short*)(cntf + NGRAPHS); // [16384]
    float* w2l     = (float*)(WT1 + 128 * 128);            // [132] (c2 at [128])
    unsigned int* pairs = (unsigned int*)(w2l + 132);      // [NCB*CAP] fixed regions
    int* csr_src   = (int*)(pairs + (size_t)NCB * CAP);    // [NCB*CAP] fixed regions
    int4* meta     = (int4*)(((size_t)(csr_src + (size_t)NCB * CAP) + 15) & ~(size_t)15);

    const int BS = 256;

    // 1. setup: weights, zeroing, graph counts
    k_misc<<<MISC_BLOCKS, BS, 0, stream>>>(W1, WT1, W2, Wlin, b2, blin, w2l,
                                           (int*)gsum, bat, cntf);
    // 2. GEMM half A || pass-1 scatter into fixed bucket regions
    k_gA_p1<<<GEMM_HALF + P1_BLOCKS, BS, 0, stream>>>(x, WT1, bufA, src, dst, bcur, pairs);
    // 3. GEMM half B || pass-2 bucket sort + rank-major meta
    k_gB_p2<<<GEMM_HALF + NCB, BS, 0, stream>>>(x, WT1, bufA, pairs, bcur, csr_src,
                                                dinv, meta);
    // 4. layer-1 gather + fused projection to scalar z
    k_gather1<<<G1_BLOCKS, BS, 0, stream>>>(bufA, csr_src, dinv, b1, w2l, meta, z);
    // 5. layer-2 + pool over scalar z
    k_g2<<<G2_BLOCKS, BS, 0, stream>>>(z, csr_src, meta, bat, gsum);
    // 6. final (trivial)
    k_final<<<(NGRAPHS + BS - 1) / BS, BS, 0, stream>>>(gsum, cntf, w2l + 128, out);
}

// Round 12
// 237.839 us; speedup vs baseline: 1.1169x; 1.0227x over previous
//
#include <hip/hip_runtime.h>

#define N_NODES   100000
#define N_EDGES   1600000
#define NFEAT     128
#define NGRAPHS   2048
#define CBSHIFT   7                        // 128 nodes per coarse bucket
#define BSZ       128                      // bucket size
#define NCB       ((N_NODES + BSZ - 1) / BSZ)         // 782
#define N_META    (NCB * BSZ)              // 100096 rank-major meta slots (96 holes)
#define CAP       2432                     // fixed bucket capacity (mean 2046, +8.5 sigma)
#define P1_EPB    4096                     // edges per p1 block
#define P1_BLOCKS ((N_EDGES + P1_EPB - 1) / P1_EPB)   // 391
#define GEMM_HALF   391
#define G1_BLOCKS 2048
#define G2_BLOCKS ((4 * N_META + 255) / 256)          // 1564
#define ZCNT      (NGRAPHS + NCB)                     // gsum|bcur = 2830
#define ZB        ((ZCNT + 255) / 256)                // 12
#define MISC_BLOCKS (17 + ZB + 8)                     // 37

typedef __attribute__((ext_vector_type(8))) short short8;
typedef __attribute__((ext_vector_type(4))) float f32x4;

// RNE float -> bf16 (finite inputs)
__device__ __forceinline__ unsigned short f2bf(float f) {
    unsigned int u = __float_as_uint(f);
    u += 0x7FFFu + ((u >> 16) & 1u);
    return (unsigned short)(u >> 16);
}

// acc[k] += s * bf16[k]  (8 bf16 packed in uint4)
__device__ __forceinline__ void acc8s(float* acc, uint4 v, float s) {
    acc[0] = fmaf(s, __uint_as_float(v.x << 16), acc[0]);
    acc[1] = fmaf(s, __uint_as_float(v.x & 0xFFFF0000u), acc[1]);
    acc[2] = fmaf(s, __uint_as_float(v.y << 16), acc[2]);
    acc[3] = fmaf(s, __uint_as_float(v.y & 0xFFFF0000u), acc[3]);
    acc[4] = fmaf(s, __uint_as_float(v.z << 16), acc[4]);
    acc[5] = fmaf(s, __uint_as_float(v.z & 0xFFFF0000u), acc[5]);
    acc[6] = fmaf(s, __uint_as_float(v.w << 16), acc[6]);
    acc[7] = fmaf(s, __uint_as_float(v.w & 0xFFFF0000u), acc[7]);
}

// ---------------- GEMM tile with feature-permuted short8 C-store ----------------
// C[r, slot 8*m16+ct] = bf16((X@W1)[r, feat ct*16+m16]) -> one 16B store per fragment
__device__ __forceinline__ void gemm_tile(const float* __restrict__ X,
                                          const unsigned short* __restrict__ WT,
                                          unsigned short* __restrict__ C,
                                          int gblk, int tid) {
    const int R0   = gblk * 128;
    const int wv   = tid >> 6;
    const int lane = tid & 63;
    const int m16  = lane & 15;
    const int quad = lane >> 4;
    const int r0 = R0 + wv * 32 + m16;
    const int r1 = r0 + 16;
    const bool ok0 = r0 < N_NODES, ok1 = r1 < N_NODES;

    f32x4 acc[2][8] = {};
    #pragma unroll
    for (int ks = 0; ks < 4; ++ks) {
        const int k0 = ks * 32 + quad * 8;
        short8 a0 = {}, a1 = {};
        if (ok0) {
            float4 f0 = *(const float4*)(X + (size_t)r0 * NFEAT + k0);
            float4 f1 = *(const float4*)(X + (size_t)r0 * NFEAT + k0 + 4);
            a0[0] = (short)f2bf(f0.x); a0[1] = (short)f2bf(f0.y);
            a0[2] = (short)f2bf(f0.z); a0[3] = (short)f2bf(f0.w);
            a0[4] = (short)f2bf(f1.x); a0[5] = (short)f2bf(f1.y);
            a0[6] = (short)f2bf(f1.z); a0[7] = (short)f2bf(f1.w);
        }
        if (ok1) {
            float4 f0 = *(const float4*)(X + (size_t)r1 * NFEAT + k0);
            float4 f1 = *(const float4*)(X + (size_t)r1 * NFEAT + k0 + 4);
            a1[0] = (short)f2bf(f0.x); a1[1] = (short)f2bf(f0.y);
            a1[2] = (short)f2bf(f0.z); a1[3] = (short)f2bf(f0.w);
            a1[4] = (short)f2bf(f1.x); a1[5] = (short)f2bf(f1.y);
            a1[6] = (short)f2bf(f1.z); a1[7] = (short)f2bf(f1.w);
        }
        #pragma unroll
        for (int ct = 0; ct < 8; ++ct) {
            short8 bb = *(const short8*)(WT + (ct * 16 + m16) * 128 + k0);
            acc[0][ct] = __builtin_amdgcn_mfma_f32_16x16x32_bf16(a0, bb, acc[0][ct], 0, 0, 0);
            acc[1][ct] = __builtin_amdgcn_mfma_f32_16x16x32_bf16(a1, bb, acc[1][ct], 0, 0, 0);
        }
    }
    #pragma unroll
    for (int t2 = 0; t2 < 2; ++t2) {
        int rbase = R0 + wv * 32 + t2 * 16 + quad * 4;
        #pragma unroll
        for (int reg = 0; reg < 4; ++reg) {
            int gr = rbase + reg;
            if (gr < N_NODES) {
                short8 v;
                #pragma unroll
                for (int ct = 0; ct < 8; ++ct)
                    v[ct] = (short)f2bf(acc[t2][ct][reg]);
                *(short8*)(C + (size_t)gr * NFEAT + m16 * 8) = v;
            }
        }
    }
}

// ---------------- multi-role setup: 0-15 WT1, 16 w2l, zeroing, graph counts ----------------
__global__ __launch_bounds__(256) void k_misc(const float* __restrict__ W1,
                                              unsigned short* __restrict__ WT1,
                                              const float* __restrict__ W2,
                                              const float* __restrict__ Wlin,
                                              const float* __restrict__ b2,
                                              const float* __restrict__ blin,
                                              float* __restrict__ w2l,
                                              int* __restrict__ zeros,
                                              const int* __restrict__ batch,
                                              float* __restrict__ cntf) {
    const int blk = blockIdx.x;
    const int t = threadIdx.x;
    if (blk < 16) {
        int base = blk * 1024 + t * 4;
        #pragma unroll
        for (int q = 0; q < 4; ++q) {
            int i = base + q;
            int n = i >> 7, k = i & 127;
            WT1[i] = f2bf(W1[k * 128 + n]);
        }
    } else if (blk == 16) {
        __shared__ float s[256];
        int i = t >> 1, half = t & 1;
        float ps = 0.f;
        for (int j = half * 64; j < half * 64 + 64; ++j)
            ps += W2[i * 128 + j] * Wlin[j];
        s[t] = ps;
        __syncthreads();
        if (!half) w2l[i] = s[t] + s[t + 1];
        __syncthreads();
        float pc = (t < 128) ? b2[t] * Wlin[t] : 0.f;
        s[t] = pc;
        __syncthreads();
        for (int off = 128; off > 0; off >>= 1) {
            if (t < off) s[t] += s[t + off];
            __syncthreads();
        }
        if (t == 0) w2l[128] = s[0] + blin[0];
    } else if (blk < 17 + ZB) {
        int i = (blk - 17) * 256 + t;
        if (i < ZCNT) zeros[i] = 0;
    } else {
        // graph node-counts via binary search on sorted batch
        int g = (blk - (17 + ZB)) * 256 + t;   // 8 blocks cover 2048
        int lo = 0, hi = N_NODES;
        while (lo < hi) { int m = (lo + hi) >> 1; if (batch[m] < g) lo = m + 1; else hi = m; }
        int lb = lo;
        lo = 0; hi = N_NODES;
        int g1 = g + 1;
        while (lo < hi) { int m = (lo + hi) >> 1; if (batch[m] < g1) lo = m + 1; else hi = m; }
        cntf[g] = fmaxf((float)(lo - lb), 1.0f);
    }
}

// ---------------- launch 2: GEMM half A || pass-1 scatter (int4 edge loads) ----------------
__global__ __launch_bounds__(256) void k_gA_p1(const float* __restrict__ X,
                                               const unsigned short* __restrict__ WT,
                                               unsigned short* __restrict__ C,
                                               const int* __restrict__ src,
                                               const int* __restrict__ dst,
                                               int* __restrict__ bcur,
                                               unsigned int* __restrict__ pairs) {
    if (blockIdx.x < GEMM_HALF) {
        gemm_tile(X, WT, C, blockIdx.x, threadIdx.x);
        return;
    }
    const int b = blockIdx.x - GEMM_HALF;     // p1 block id [0,391)
    __shared__ int hist[NCB], base[NCB], cur[NCB];
    const int t = threadIdx.x;
    for (int i = t; i < NCB; i += 256) { hist[i] = 0; cur[i] = 0; }
    __syncthreads();
    // e0/e1 both divisible by 4 (P1_EPB=4096, N_EDGES=1.6M)
    const int e0 = b * P1_EPB;
    const int e1 = min(e0 + P1_EPB, N_EDGES);
    const int q0 = e0 >> 2, q1 = e1 >> 2;
    const int4* dst4 = (const int4*)dst;
    const int4* src4 = (const int4*)src;
    for (int q = q0 + t; q < q1; q += 256) {
        int4 d4 = dst4[q];
        atomicAdd(&hist[d4.x >> CBSHIFT], 1);
        atomicAdd(&hist[d4.y >> CBSHIFT], 1);
        atomicAdd(&hist[d4.z >> CBSHIFT], 1);
        atomicAdd(&hist[d4.w >> CBSHIFT], 1);
    }
    __syncthreads();
    // staggered reservation order: spread per-bucket atomic queues
    const int off0 = (b * 89) % NCB;
    for (int k = t; k < NCB; k += 256) {
        int i = k + off0;
        if (i >= NCB) i -= NCB;
        int c = hist[i];
        base[i] = c ? (i * CAP + atomicAdd(&bcur[i], c)) : 0;
    }
    __syncthreads();
    for (int q = q0 + t; q < q1; q += 256) {
        int4 d4 = dst4[q];
        int4 s4 = src4[q];
        #pragma unroll
        for (int u = 0; u < 4; ++u) {
            int d = (u == 0) ? d4.x : (u == 1) ? d4.y : (u == 2) ? d4.z : d4.w;
            int sv = (u == 0) ? s4.x : (u == 1) ? s4.y : (u == 2) ? s4.z : s4.w;
            int bb = d >> CBSHIFT;
            int r = atomicAdd(&cur[bb], 1);
            int idx = base[bb] + r;
            if (idx < (bb + 1) * CAP)   // overflow guard (P ~ 1e-13)
                pairs[idx] = (unsigned int)sv | ((unsigned int)(d & (BSZ - 1)) << 17);
        }
    }
}

// ---------------- launch 3: GEMM half B || pass-2 bucket sort + rank-major meta ----------------
__global__ __launch_bounds__(256) void k_gB_p2(const float* __restrict__ X,
                                               const unsigned short* __restrict__ WT,
                                               unsigned short* __restrict__ C,
                                               const unsigned int* __restrict__ pairs,
                                               const int* __restrict__ bcur,
                                               int* __restrict__ csr_src,
                                               float* __restrict__ dinv,
                                               int4* __restrict__ meta) {
    if (blockIdx.x < GEMM_HALF) {
        gemm_tile(X, WT, C, blockIdx.x + GEMM_HALF, threadIdx.x);
        return;
    }
    const int b = blockIdx.x - GEMM_HALF;     // bucket id [0,782)
    __shared__ int hist[BSZ], sst[BSZ], cur[BSZ], s[BSZ], dh[64], dhc[64];
    const int t = threadIdx.x;
    const int cnt_b = min(bcur[b], CAP);
    const int beg = b * CAP;                  // divisible by 4 (CAP=2432)
    const int end = beg + cnt_b;
    const int end4 = beg + (cnt_b & ~3);
    if (t < BSZ) { hist[t] = 0; cur[t] = 0; }
    if (t < 64) { dh[t] = 0; dhc[t] = 0; }
    __syncthreads();
    for (int i = beg + 4 * t; i < end4; i += 1024) {
        uint4 pv = *(const uint4*)(pairs + i);
        atomicAdd(&hist[pv.x >> 17], 1);
        atomicAdd(&hist[pv.y >> 17], 1);
        atomicAdd(&hist[pv.z >> 17], 1);
        atomicAdd(&hist[pv.w >> 17], 1);
    }
    for (int i = end4 + t; i < end; i += 256)
        atomicAdd(&hist[pairs[i] >> 17], 1);
    __syncthreads();
    int v = (t < BSZ) ? hist[t] : 0;
    if (t < BSZ) s[t] = v;
    __syncthreads();
    for (int off = 1; off < BSZ; off <<= 1) {
        int x = (t >= off && t < BSZ) ? s[t - off] : 0;
        __syncthreads();
        if (t < BSZ) s[t] += x;
        __syncthreads();
    }
    if (t < BSZ) sst[t] = s[t] - v;
    __syncthreads();
    const int node = (b << CBSHIFT) + t;
    const bool valid = (t < BSZ) && (node < N_NODES);
    if (valid) {
        dinv[node] = rsqrtf((float)v + 1.0f);
        atomicAdd(&dh[63 - min(v, 63)], 1);
    }
    for (int i = beg + 4 * t; i < end4; i += 1024) {
        uint4 pv = *(const uint4*)(pairs + i);
        #pragma unroll
        for (int u = 0; u < 4; ++u) {
            unsigned int p = (u == 0) ? pv.x : (u == 1) ? pv.y : (u == 2) ? pv.z : pv.w;
            int dl = p >> 17;
            int r = atomicAdd(&cur[dl], 1);
            csr_src[beg + sst[dl] + r] = (int)(p & 0x1FFFFu);
        }
    }
    for (int i = end4 + t; i < end; i += 256) {
        unsigned int pv = pairs[i];
        int dl = pv >> 17;
        int r = atomicAdd(&cur[dl], 1);
        csr_src[beg + sst[dl] + r] = (int)(pv & 0x1FFFFu);
    }
    __syncthreads();
    // bucket-local degree sort: 64-bin inclusive scan of dh
    if (t < 64) s[t] = dh[t];
    __syncthreads();
    for (int off = 1; off < 64; off <<= 1) {
        int x = (t >= off && t < 64) ? s[t - off] : 0;
        __syncthreads();
        if (t < 64) s[t] += x;
        __syncthreads();
    }
    if (valid) {
        int bin = 63 - min(v, 63);
        int r = atomicAdd(&dhc[bin], 1);
        int rank = s[bin] - dh[bin] + r;           // exclusive prefix + within-bin slot
        meta[(size_t)rank * NCB + b] =
            make_int4(beg + sst[t], v, __float_as_int(rsqrtf((float)v + 1.0f)), node);
    } else if (t < BSZ) {
        meta[(size_t)t * NCB + b] = make_int4(0, 0, 0, -1);
    }
}

// ---------------- gather layer 1 (per-edge dinv) + fused z projection ----------------
// static grid-stride; masked full chunks; A/B double-buffered gathers (proven 63 us)
// table is feature-permuted: acc[j] of lane p holds feat 16*j+p -> permuted b/w preload
__global__ __launch_bounds__(256) void k_gather1(const unsigned short* __restrict__ xwb,
                                                 const int* __restrict__ csr_src,
                                                 const float* __restrict__ dinv,
                                                 const float* __restrict__ b,
                                                 const float* __restrict__ w2l,
                                                 const int4* __restrict__ meta,
                                                 float* __restrict__ z) {
    const int t     = threadIdx.x;
    const int lane  = t & 63;
    const int p     = lane & 15;
    const int gbase = lane & 48;
    const int j0    = p & 7;
    const int ngroups = G1_BLOCKS * 16;
    int gid = blockIdx.x * 16 + (t >> 4);
    const uint4* tab = (const uint4*)xwb;
    float bl[8], wl[8];
    #pragma unroll
    for (int j = 0; j < 8; ++j) { bl[j] = b[16 * j + p]; wl[j] = w2l[16 * j + p]; }

    for (int nidx = gid; nidx < N_META; nidx += ngroups) {
        const int4 md = meta[nidx];
        const int node  = md.w;
        if (node < 0) continue;                  // hole slot
        const int beg   = md.x;
        const int cnt   = md.y;
        const float dvn = __int_as_float(md.z);
        float acc[8] = {};
        acc8s(acc, tab[(size_t)node * 16 + p], dvn);   // self loop
        const int nch = (cnt + 7) >> 3;
        if (nch) {
            int myA; float dvA; uint4 vA[8];
            int myB; float dvB; uint4 vB[8];
            {   // chunk 0 -> A
                bool vld = j0 < cnt;
                int jj = vld ? j0 : 0;
                int sld = csr_src[beg + jj];
                myA = vld ? sld : node;
                float dv = dinv[myA];
                dvA = vld ? dv : 0.f;
                #pragma unroll
                for (int q = 0; q < 8; ++q) {
                    int idx = __shfl(myA, gbase + q);
                    vA[q] = tab[(size_t)idx * 16 + p];
                }
            }
            int c = 0;
            for (;;) {
                const bool hb = (c + 1 < nch);
                if (hb) {
                    int j = (c + 1) * 8 + j0;
                    bool vld = j < cnt;
                    int jj = vld ? j : 0;
                    int sld = csr_src[beg + jj];
                    myB = vld ? sld : node;
                    float dv = dinv[myB];
                    dvB = vld ? dv : 0.f;
                    #pragma unroll
                    for (int q = 0; q < 8; ++q) {
                        int idx = __shfl(myB, gbase + q);
                        vB[q] = tab[(size_t)idx * 16 + p];
                    }
                }
                #pragma unroll
                for (int q = 0; q < 8; ++q) {
                    float sv = __shfl(dvA, gbase + q);
                    acc8s(acc, vA[q], sv);
                }
                ++c;
                if (!hb) break;
                const bool ha = (c + 1 < nch);
                if (ha) {
                    int j = (c + 1) * 8 + j0;
                    bool vld = j < cnt;
                    int jj = vld ? j : 0;
                    int sld = csr_src[beg + jj];
                    myA = vld ? sld : node;
                    float dv = dinv[myA];
                    dvA = vld ? dv : 0.f;
                    #pragma unroll
                    for (int q = 0; q < 8; ++q) {
                        int idx = __shfl(myA, gbase + q);
                        vA[q] = tab[(size_t)idx * 16 + p];
                    }
                }
                #pragma unroll
                for (int q = 0; q < 8; ++q) {
                    float sv = __shfl(dvB, gbase + q);
                    acc8s(acc, vB[q], sv);
                }
                ++c;
                if (!ha) break;
            }
        }
        float s = 0.f;
        #pragma unroll
        for (int j = 0; j < 8; ++j)
            s = fmaf(fmaxf(fmaf(acc[j], dvn, bl[j]), 0.f), wl[j], s);
        s += __shfl_xor(s, 1);
        s += __shfl_xor(s, 2);
        s += __shfl_xor(s, 4);
        s += __shfl_xor(s, 8);
        if (p == 0) z[node] = s * dvn;
    }
}

// ---------------- layer 2 + pool over scalars: 4 lanes per node (no fence) ----------------
__global__ __launch_bounds__(256) void k_g2(const float* __restrict__ z,
                                            const int* __restrict__ csr_src,
                                            const int4* __restrict__ meta,
                                            const int* __restrict__ batch,
                                            float* __restrict__ gsum) {
    int tid = blockIdx.x * blockDim.x + threadIdx.x;
    int nidx = tid >> 2;
    int q = tid & 3;
    if (nidx >= N_META) return;
    int4 md = meta[nidx];
    const int node = md.w;
    if (node < 0) return;                        // hole slot
    const int beg = md.x, cnt = md.y;
    const float dvn = __int_as_float(md.z);
    float a = (q == 0) ? z[node] : 0.f;
    for (int j = q; j < cnt; j += 4)
        a += z[csr_src[beg + j]];
    a += __shfl_xor(a, 1);
    a += __shfl_xor(a, 2);
    if (q == 0) atomicAdd(&gsum[batch[node]], a * dvn);
}

// ---------------- final: trivial (counts precomputed in k_misc) ----------------
__global__ void k_final(const float* __restrict__ gsum, const float* __restrict__ cntf,
                        const float* __restrict__ c2, float* __restrict__ out) {
    int g = blockIdx.x * blockDim.x + threadIdx.x;
    if (g >= NGRAPHS) return;
    out[g] = gsum[g] / cntf[g] + c2[0];
}

extern "C" void kernel_launch(void* const* d_in, const int* in_sizes, int n_in,
                              void* d_out, int out_size, void* d_ws, size_t ws_size,
                              hipStream_t stream) {
    const float* x    = (const float*)d_in[0];
    const int*   ei   = (const int*)d_in[1];
    const int*   bat  = (const int*)d_in[2];
    const float* W1   = (const float*)d_in[3];
    const float* b1   = (const float*)d_in[4];
    const float* W2   = (const float*)d_in[5];
    const float* b2   = (const float*)d_in[6];
    const float* Wlin = (const float*)d_in[7];
    const float* blin = (const float*)d_in[8];
    float* out = (float*)d_out;

    const int* src = ei;
    const int* dst = ei + N_EDGES;

    // ---- workspace layout ----
    const size_t NF = (size_t)N_NODES * NFEAT;
    unsigned short* bufA = (unsigned short*)d_ws;          // bf16 xw1 table (25.6 MB)
    float* z       = (float*)(bufA + NF);                  // [N]
    float* dinv    = z + N_NODES;                          // [N]
    // zeroed-by-misc region (contiguous): gsum | bcur
    float* gsum    = dinv + N_NODES;                       // [G]
    int* bcur      = (int*)(gsum + NGRAPHS);               // [NCB] bucket fill cursors
    float* cntf    = (float*)(bcur + NCB);                 // [G] (written by misc)
    unsigned short* WT1 = (unsigned short*)(cntf + NGRAPHS); // [16384]
    float* w2l     = (float*)(WT1 + 128 * 128);            // [132] (c2 at [128])
    unsigned int* pairs = (unsigned int*)(w2l + 132);      // [NCB*CAP] fixed regions
    int* csr_src   = (int*)(pairs + (size_t)NCB * CAP);    // [NCB*CAP] fixed regions
    int4* meta     = (int4*)(((size_t)(csr_src + (size_t)NCB * CAP) + 15) & ~(size_t)15);

    const int BS = 256;

    // 1. setup: weights, zeroing, graph counts
    k_misc<<<MISC_BLOCKS, BS, 0, stream>>>(W1, WT1, W2, Wlin, b2, blin, w2l,
                                           (int*)gsum, bat, cntf);
    // 2. GEMM half A || pass-1 scatter into fixed bucket regions (391+391 blocks)
    k_gA_p1<<<GEMM_HALF + P1_BLOCKS, BS, 0, stream>>>(x, WT1, bufA, src, dst, bcur, pairs);
    // 3. GEMM half B || pass-2 bucket sort + rank-major meta
    k_gB_p2<<<GEMM_HALF + NCB, BS, 0, stream>>>(x, WT1, bufA, pairs, bcur, csr_src,
                                                dinv, meta);
    // 4. layer-1 gather + fused projection to scalar z
    k_gather1<<<G1_BLOCKS, BS, 0, stream>>>(bufA, csr_src, dinv, b1, w2l, meta, z);
    // 5. layer-2 + pool over scalar z
    k_g2<<<G2_BLOCKS, BS, 0, stream>>>(z, csr_src, meta, bat, gsum);
    // 6. final (trivial)
    k_final<<<(NGRAPHS + BS - 1) / BS, BS, 0, stream>>>(gsum, cntf, w2l + 128, out);
}

// Round 13
// 228.875 us; speedup vs baseline: 1.1607x; 1.0392x over previous
//
#include <hip/hip_runtime.h>

#define N_NODES   100000
#define N_EDGES   1600000
#define NFEAT     128
#define NGRAPHS   2048
#define CBSHIFT   7                        // 128 nodes per coarse bucket
#define BSZ       128                      // bucket size
#define NCB       ((N_NODES + BSZ - 1) / BSZ)         // 782
#define N_META    (NCB * BSZ)              // 100096 rank-major meta slots (96 holes)
#define CAP       2432                     // fixed bucket capacity (mean 2046, +8.5 sigma)
#define P1_EPB    4096                     // edges per p1 block
#define P1_BLOCKS ((N_EDGES + P1_EPB - 1) / P1_EPB)   // 391
#define GEMM_HALF   391
#define G1_BLOCKS 2048
#define G2_BLOCKS ((4 * N_NODES + 255) / 256)         // 1563 (node-order, no holes)
#define ZCNT      (NGRAPHS + NCB)                     // gsum|bcur = 2830
#define ZB        ((ZCNT + 255) / 256)                // 12
#define MISC_BLOCKS (17 + ZB + 8)                     // 37

typedef __attribute__((ext_vector_type(8))) short short8;
typedef __attribute__((ext_vector_type(4))) float f32x4;

// RNE float -> bf16 (finite inputs)
__device__ __forceinline__ unsigned short f2bf(float f) {
    unsigned int u = __float_as_uint(f);
    u += 0x7FFFu + ((u >> 16) & 1u);
    return (unsigned short)(u >> 16);
}

// acc[k] += s * bf16[k]  (8 bf16 packed in uint4)
__device__ __forceinline__ void acc8s(float* acc, uint4 v, float s) {
    acc[0] = fmaf(s, __uint_as_float(v.x << 16), acc[0]);
    acc[1] = fmaf(s, __uint_as_float(v.x & 0xFFFF0000u), acc[1]);
    acc[2] = fmaf(s, __uint_as_float(v.y << 16), acc[2]);
    acc[3] = fmaf(s, __uint_as_float(v.y & 0xFFFF0000u), acc[3]);
    acc[4] = fmaf(s, __uint_as_float(v.z << 16), acc[4]);
    acc[5] = fmaf(s, __uint_as_float(v.z & 0xFFFF0000u), acc[5]);
    acc[6] = fmaf(s, __uint_as_float(v.w << 16), acc[6]);
    acc[7] = fmaf(s, __uint_as_float(v.w & 0xFFFF0000u), acc[7]);
}

// ---------------- GEMM tile with feature-permuted short8 C-store ----------------
// C[r, slot 8*m16+ct] = bf16((X@W1)[r, feat ct*16+m16]) -> one 16B store per fragment
__device__ __forceinline__ void gemm_tile(const float* __restrict__ X,
                                          const unsigned short* __restrict__ WT,
                                          unsigned short* __restrict__ C,
                                          int gblk, int tid) {
    const int R0   = gblk * 128;
    const int wv   = tid >> 6;
    const int lane = tid & 63;
    const int m16  = lane & 15;
    const int quad = lane >> 4;
    const int r0 = R0 + wv * 32 + m16;
    const int r1 = r0 + 16;
    const bool ok0 = r0 < N_NODES, ok1 = r1 < N_NODES;

    f32x4 acc[2][8] = {};
    #pragma unroll
    for (int ks = 0; ks < 4; ++ks) {
        const int k0 = ks * 32 + quad * 8;
        short8 a0 = {}, a1 = {};
        if (ok0) {
            float4 f0 = *(const float4*)(X + (size_t)r0 * NFEAT + k0);
            float4 f1 = *(const float4*)(X + (size_t)r0 * NFEAT + k0 + 4);
            a0[0] = (short)f2bf(f0.x); a0[1] = (short)f2bf(f0.y);
            a0[2] = (short)f2bf(f0.z); a0[3] = (short)f2bf(f0.w);
            a0[4] = (short)f2bf(f1.x); a0[5] = (short)f2bf(f1.y);
            a0[6] = (short)f2bf(f1.z); a0[7] = (short)f2bf(f1.w);
        }
        if (ok1) {
            float4 f0 = *(const float4*)(X + (size_t)r1 * NFEAT + k0);
            float4 f1 = *(const float4*)(X + (size_t)r1 * NFEAT + k0 + 4);
            a1[0] = (short)f2bf(f0.x); a1[1] = (short)f2bf(f0.y);
            a1[2] = (short)f2bf(f0.z); a1[3] = (short)f2bf(f0.w);
            a1[4] = (short)f2bf(f1.x); a1[5] = (short)f2bf(f1.y);
            a1[6] = (short)f2bf(f1.z); a1[7] = (short)f2bf(f1.w);
        }
        #pragma unroll
        for (int ct = 0; ct < 8; ++ct) {
            short8 bb = *(const short8*)(WT + (ct * 16 + m16) * 128 + k0);
            acc[0][ct] = __builtin_amdgcn_mfma_f32_16x16x32_bf16(a0, bb, acc[0][ct], 0, 0, 0);
            acc[1][ct] = __builtin_amdgcn_mfma_f32_16x16x32_bf16(a1, bb, acc[1][ct], 0, 0, 0);
        }
    }
    #pragma unroll
    for (int t2 = 0; t2 < 2; ++t2) {
        int rbase = R0 + wv * 32 + t2 * 16 + quad * 4;
        #pragma unroll
        for (int reg = 0; reg < 4; ++reg) {
            int gr = rbase + reg;
            if (gr < N_NODES) {
                short8 v;
                #pragma unroll
                for (int ct = 0; ct < 8; ++ct)
                    v[ct] = (short)f2bf(acc[t2][ct][reg]);
                *(short8*)(C + (size_t)gr * NFEAT + m16 * 8) = v;
            }
        }
    }
}

// ---------------- multi-role setup: 0-15 WT1, 16 w2l, zeroing, graph counts ----------------
__global__ __launch_bounds__(256) void k_misc(const float* __restrict__ W1,
                                              unsigned short* __restrict__ WT1,
                                              const float* __restrict__ W2,
                                              const float* __restrict__ Wlin,
                                              const float* __restrict__ b2,
                                              const float* __restrict__ blin,
                                              float* __restrict__ w2l,
                                              int* __restrict__ zeros,
                                              const int* __restrict__ batch,
                                              float* __restrict__ cntf) {
    const int blk = blockIdx.x;
    const int t = threadIdx.x;
    if (blk < 16) {
        int base = blk * 1024 + t * 4;
        #pragma unroll
        for (int q = 0; q < 4; ++q) {
            int i = base + q;
            int n = i >> 7, k = i & 127;
            WT1[i] = f2bf(W1[k * 128 + n]);
        }
    } else if (blk == 16) {
        __shared__ float s[256];
        int i = t >> 1, half = t & 1;
        float ps = 0.f;
        for (int j = half * 64; j < half * 64 + 64; ++j)
            ps += W2[i * 128 + j] * Wlin[j];
        s[t] = ps;
        __syncthreads();
        if (!half) w2l[i] = s[t] + s[t + 1];
        __syncthreads();
        float pc = (t < 128) ? b2[t] * Wlin[t] : 0.f;
        s[t] = pc;
        __syncthreads();
        for (int off = 128; off > 0; off >>= 1) {
            if (t < off) s[t] += s[t + off];
            __syncthreads();
        }
        if (t == 0) w2l[128] = s[0] + blin[0];
    } else if (blk < 17 + ZB) {
        int i = (blk - 17) * 256 + t;
        if (i < ZCNT) zeros[i] = 0;
    } else {
        // graph node-counts via binary search on sorted batch
        int g = (blk - (17 + ZB)) * 256 + t;   // 8 blocks cover 2048
        int lo = 0, hi = N_NODES;
        while (lo < hi) { int m = (lo + hi) >> 1; if (batch[m] < g) lo = m + 1; else hi = m; }
        int lb = lo;
        lo = 0; hi = N_NODES;
        int g1 = g + 1;
        while (lo < hi) { int m = (lo + hi) >> 1; if (batch[m] < g1) lo = m + 1; else hi = m; }
        cntf[g] = fmaxf((float)(lo - lb), 1.0f);
    }
}

// ---------------- launch 2: GEMM half A || pass-1 scatter (int4 edge loads) ----------------
__global__ __launch_bounds__(256) void k_gA_p1(const float* __restrict__ X,
                                               const unsigned short* __restrict__ WT,
                                               unsigned short* __restrict__ C,
                                               const int* __restrict__ src,
                                               const int* __restrict__ dst,
                                               int* __restrict__ bcur,
                                               unsigned int* __restrict__ pairs) {
    if (blockIdx.x < GEMM_HALF) {
        gemm_tile(X, WT, C, blockIdx.x, threadIdx.x);
        return;
    }
    const int b = blockIdx.x - GEMM_HALF;     // p1 block id [0,391)
    __shared__ int hist[NCB], base[NCB], cur[NCB];
    const int t = threadIdx.x;
    for (int i = t; i < NCB; i += 256) { hist[i] = 0; cur[i] = 0; }
    __syncthreads();
    // e0/e1 both divisible by 4 (P1_EPB=4096, N_EDGES=1.6M)
    const int e0 = b * P1_EPB;
    const int e1 = min(e0 + P1_EPB, N_EDGES);
    const int q0 = e0 >> 2, q1 = e1 >> 2;
    const int4* dst4 = (const int4*)dst;
    const int4* src4 = (const int4*)src;
    for (int q = q0 + t; q < q1; q += 256) {
        int4 d4 = dst4[q];
        atomicAdd(&hist[d4.x >> CBSHIFT], 1);
        atomicAdd(&hist[d4.y >> CBSHIFT], 1);
        atomicAdd(&hist[d4.z >> CBSHIFT], 1);
        atomicAdd(&hist[d4.w >> CBSHIFT], 1);
    }
    __syncthreads();
    // staggered reservation order: spread per-bucket atomic queues
    const int off0 = (b * 89) % NCB;
    for (int k = t; k < NCB; k += 256) {
        int i = k + off0;
        if (i >= NCB) i -= NCB;
        int c = hist[i];
        base[i] = c ? (i * CAP + atomicAdd(&bcur[i], c)) : 0;
    }
    __syncthreads();
    for (int q = q0 + t; q < q1; q += 256) {
        int4 d4 = dst4[q];
        int4 s4 = src4[q];
        #pragma unroll
        for (int u = 0; u < 4; ++u) {
            int d = (u == 0) ? d4.x : (u == 1) ? d4.y : (u == 2) ? d4.z : d4.w;
            int sv = (u == 0) ? s4.x : (u == 1) ? s4.y : (u == 2) ? s4.z : s4.w;
            int bb = d >> CBSHIFT;
            int r = atomicAdd(&cur[bb], 1);
            int idx = base[bb] + r;
            if (idx < (bb + 1) * CAP)   // overflow guard (P ~ 1e-13)
                pairs[idx] = (unsigned int)sv | ((unsigned int)(d & (BSZ - 1)) << 17);
        }
    }
}

// ---------------- launch 3: GEMM half B || pass-2 bucket sort + rank-major meta ----------------
__global__ __launch_bounds__(256) void k_gB_p2(const float* __restrict__ X,
                                               const unsigned short* __restrict__ WT,
                                               unsigned short* __restrict__ C,
                                               const unsigned int* __restrict__ pairs,
                                               const int* __restrict__ bcur,
                                               int* __restrict__ csr_src,
                                               float* __restrict__ dinv,
                                               int4* __restrict__ meta,
                                               int2* __restrict__ nm) {
    if (blockIdx.x < GEMM_HALF) {
        gemm_tile(X, WT, C, blockIdx.x + GEMM_HALF, threadIdx.x);
        return;
    }
    const int b = blockIdx.x - GEMM_HALF;     // bucket id [0,782)
    __shared__ int hist[BSZ], sst[BSZ], cur[BSZ], s[BSZ], dh[64], dhc[64];
    const int t = threadIdx.x;
    const int cnt_b = min(bcur[b], CAP);
    const int beg = b * CAP;                  // divisible by 4 (CAP=2432)
    const int end = beg + cnt_b;
    const int end4 = beg + (cnt_b & ~3);
    if (t < BSZ) { hist[t] = 0; cur[t] = 0; }
    if (t < 64) { dh[t] = 0; dhc[t] = 0; }
    __syncthreads();
    for (int i = beg + 4 * t; i < end4; i += 1024) {
        uint4 pv = *(const uint4*)(pairs + i);
        atomicAdd(&hist[pv.x >> 17], 1);
        atomicAdd(&hist[pv.y >> 17], 1);
        atomicAdd(&hist[pv.z >> 17], 1);
        atomicAdd(&hist[pv.w >> 17], 1);
    }
    for (int i = end4 + t; i < end; i += 256)
        atomicAdd(&hist[pairs[i] >> 17], 1);
    __syncthreads();
    int v = (t < BSZ) ? hist[t] : 0;
    if (t < BSZ) s[t] = v;
    __syncthreads();
    for (int off = 1; off < BSZ; off <<= 1) {
        int x = (t >= off && t < BSZ) ? s[t - off] : 0;
        __syncthreads();
        if (t < BSZ) s[t] += x;
        __syncthreads();
    }
    if (t < BSZ) sst[t] = s[t] - v;
    __syncthreads();
    const int node = (b << CBSHIFT) + t;
    const bool valid = (t < BSZ) && (node < N_NODES);
    if (valid) {
        dinv[node] = rsqrtf((float)v + 1.0f);
        nm[node] = make_int2(beg + sst[t], v);     // node-indexed row meta for g2
        atomicAdd(&dh[63 - min(v, 63)], 1);
    }
    for (int i = beg + 4 * t; i < end4; i += 1024) {
        uint4 pv = *(const uint4*)(pairs + i);
        #pragma unroll
        for (int u = 0; u < 4; ++u) {
            unsigned int p = (u == 0) ? pv.x : (u == 1) ? pv.y : (u == 2) ? pv.z : pv.w;
            int dl = p >> 17;
            int r = atomicAdd(&cur[dl], 1);
            csr_src[beg + sst[dl] + r] = (int)(p & 0x1FFFFu);
        }
    }
    for (int i = end4 + t; i < end; i += 256) {
        unsigned int pv = pairs[i];
        int dl = pv >> 17;
        int r = atomicAdd(&cur[dl], 1);
        csr_src[beg + sst[dl] + r] = (int)(pv & 0x1FFFFu);
    }
    __syncthreads();
    // bucket-local degree sort: 64-bin inclusive scan of dh
    if (t < 64) s[t] = dh[t];
    __syncthreads();
    for (int off = 1; off < 64; off <<= 1) {
        int x = (t >= off && t < 64) ? s[t - off] : 0;
        __syncthreads();
        if (t < 64) s[t] += x;
        __syncthreads();
    }
    if (valid) {
        int bin = 63 - min(v, 63);
        int r = atomicAdd(&dhc[bin], 1);
        int rank = s[bin] - dh[bin] + r;           // exclusive prefix + within-bin slot
        meta[(size_t)rank * NCB + b] =
            make_int4(beg + sst[t], v, __float_as_int(rsqrtf((float)v + 1.0f)), node);
    } else if (t < BSZ) {
        meta[(size_t)t * NCB + b] = make_int4(0, 0, 0, -1);
    }
}

// ---------------- gather layer 1 (per-edge dinv) + fused z projection ----------------
// static grid-stride; masked full chunks; A/B double-buffered gathers (proven 63 us)
// table is feature-permuted: acc[j] of lane p holds feat 16*j+p -> permuted b/w preload
__global__ __launch_bounds__(256) void k_gather1(const unsigned short* __restrict__ xwb,
                                                 const int* __restrict__ csr_src,
                                                 const float* __restrict__ dinv,
                                                 const float* __restrict__ b,
                                                 const float* __restrict__ w2l,
                                                 const int4* __restrict__ meta,
                                                 float* __restrict__ z) {
    const int t     = threadIdx.x;
    const int lane  = t & 63;
    const int p     = lane & 15;
    const int gbase = lane & 48;
    const int j0    = p & 7;
    const int ngroups = G1_BLOCKS * 16;
    int gid = blockIdx.x * 16 + (t >> 4);
    const uint4* tab = (const uint4*)xwb;
    float bl[8], wl[8];
    #pragma unroll
    for (int j = 0; j < 8; ++j) { bl[j] = b[16 * j + p]; wl[j] = w2l[16 * j + p]; }

    for (int nidx = gid; nidx < N_META; nidx += ngroups) {
        const int4 md = meta[nidx];
        const int node  = md.w;
        if (node < 0) continue;                  // hole slot
        const int beg   = md.x;
        const int cnt   = md.y;
        const float dvn = __int_as_float(md.z);
        float acc[8] = {};
        acc8s(acc, tab[(size_t)node * 16 + p], dvn);   // self loop
        const int nch = (cnt + 7) >> 3;
        if (nch) {
            int myA; float dvA; uint4 vA[8];
            int myB; float dvB; uint4 vB[8];
            {   // chunk 0 -> A
                bool vld = j0 < cnt;
                int jj = vld ? j0 : 0;
                int sld = csr_src[beg + jj];
                myA = vld ? sld : node;
                float dv = dinv[myA];
                dvA = vld ? dv : 0.f;
                #pragma unroll
                for (int q = 0; q < 8; ++q) {
                    int idx = __shfl(myA, gbase + q);
                    vA[q] = tab[(size_t)idx * 16 + p];
                }
            }
            int c = 0;
            for (;;) {
                const bool hb = (c + 1 < nch);
                if (hb) {
                    int j = (c + 1) * 8 + j0;
                    bool vld = j < cnt;
                    int jj = vld ? j : 0;
                    int sld = csr_src[beg + jj];
                    myB = vld ? sld : node;
                    float dv = dinv[myB];
                    dvB = vld ? dv : 0.f;
                    #pragma unroll
                    for (int q = 0; q < 8; ++q) {
                        int idx = __shfl(myB, gbase + q);
                        vB[q] = tab[(size_t)idx * 16 + p];
                    }
                }
                #pragma unroll
                for (int q = 0; q < 8; ++q) {
                    float sv = __shfl(dvA, gbase + q);
                    acc8s(acc, vA[q], sv);
                }
                ++c;
                if (!hb) break;
                const bool ha = (c + 1 < nch);
                if (ha) {
                    int j = (c + 1) * 8 + j0;
                    bool vld = j < cnt;
                    int jj = vld ? j : 0;
                    int sld = csr_src[beg + jj];
                    myA = vld ? sld : node;
                    float dv = dinv[myA];
                    dvA = vld ? dv : 0.f;
                    #pragma unroll
                    for (int q = 0; q < 8; ++q) {
                        int idx = __shfl(myA, gbase + q);
                        vA[q] = tab[(size_t)idx * 16 + p];
                    }
                }
                #pragma unroll
                for (int q = 0; q < 8; ++q) {
                    float sv = __shfl(dvB, gbase + q);
                    acc8s(acc, vB[q], sv);
                }
                ++c;
                if (!ha) break;
            }
        }
        float s = 0.f;
        #pragma unroll
        for (int j = 0; j < 8; ++j)
            s = fmaf(fmaxf(fmaf(acc[j], dvn, bl[j]), 0.f), wl[j], s);
        s += __shfl_xor(s, 1);
        s += __shfl_xor(s, 2);
        s += __shfl_xor(s, 4);
        s += __shfl_xor(s, 8);
        if (p == 0) z[node] = s * dvn;
    }
}

// ---------------- layer 2 + pool: node-order, block-local LDS graph accumulation ----------------
// batch sorted by node -> 64 consecutive nodes span ~2 graphs; sequential csr reads;
// ~3 global atomics per block instead of 64
__global__ __launch_bounds__(256) void k_g2(const float* __restrict__ z,
                                            const int* __restrict__ csr_src,
                                            const int2* __restrict__ nm,
                                            const float* __restrict__ dinv,
                                            const int* __restrict__ batch,
                                            float* __restrict__ gsum) {
    __shared__ float lgs[64];
    __shared__ int sg0;
    const int t = threadIdx.x;
    if (t < 64) lgs[t] = 0.f;
    const int node0 = blockIdx.x * 64;
    if (t == 0) sg0 = batch[node0];
    __syncthreads();
    const int g0 = sg0;
    const int node = node0 + (t >> 2);
    const int q = t & 3;
    if (node < N_NODES) {
        int2 m = nm[node];
        const int beg = m.x, cnt = m.y;
        float a = (q == 0) ? z[node] : 0.f;
        for (int j = q; j < cnt; j += 4)
            a += z[csr_src[beg + j]];
        a += __shfl_xor(a, 1);
        a += __shfl_xor(a, 2);
        if (q == 0) {
            float val = a * dinv[node];
            int rel = batch[node] - g0;
            if (rel < 64) atomicAdd(&lgs[rel], val);
            else atomicAdd(&gsum[batch[node]], val);   // pathological span fallback
        }
    }
    __syncthreads();
    if (t < 64 && lgs[t] != 0.f) atomicAdd(&gsum[g0 + t], lgs[t]);
}

// ---------------- final: trivial (counts precomputed in k_misc) ----------------
__global__ void k_final(const float* __restrict__ gsum, const float* __restrict__ cntf,
                        const float* __restrict__ c2, float* __restrict__ out) {
    int g = blockIdx.x * blockDim.x + threadIdx.x;
    if (g >= NGRAPHS) return;
    out[g] = gsum[g] / cntf[g] + c2[0];
}

extern "C" void kernel_launch(void* const* d_in, const int* in_sizes, int n_in,
                              void* d_out, int out_size, void* d_ws, size_t ws_size,
                              hipStream_t stream) {
    const float* x    = (const float*)d_in[0];
    const int*   ei   = (const int*)d_in[1];
    const int*   bat  = (const int*)d_in[2];
    const float* W1   = (const float*)d_in[3];
    const float* b1   = (const float*)d_in[4];
    const float* W2   = (const float*)d_in[5];
    const float* b2   = (const float*)d_in[6];
    const float* Wlin = (const float*)d_in[7];
    const float* blin = (const float*)d_in[8];
    float* out = (float*)d_out;

    const int* src = ei;
    const int* dst = ei + N_EDGES;

    // ---- workspace layout ----
    const size_t NF = (size_t)N_NODES * NFEAT;
    unsigned short* bufA = (unsigned short*)d_ws;          // bf16 xw1 table (25.6 MB)
    float* z       = (float*)(bufA + NF);                  // [N]
    float* dinv    = z + N_NODES;                          // [N]
    // zeroed-by-misc region (contiguous): gsum | bcur
    float* gsum    = dinv + N_NODES;                       // [G]
    int* bcur      = (int*)(gsum + NGRAPHS);               // [NCB] bucket fill cursors
    float* cntf    = (float*)(bcur + NCB);                 // [G] (written by misc)
    unsigned short* WT1 = (unsigned short*)(cntf + NGRAPHS); // [16384]
    float* w2l     = (float*)(WT1 + 128 * 128);            // [132] (c2 at [128])
    unsigned int* pairs = (unsigned int*)(w2l + 132);      // [NCB*CAP] fixed regions
    int* csr_src   = (int*)(pairs + (size_t)NCB * CAP);    // [NCB*CAP] fixed regions
    int4* meta     = (int4*)(((size_t)(csr_src + (size_t)NCB * CAP) + 15) & ~(size_t)15);
    int2* nm       = (int2*)(meta + N_META);               // [N] node-indexed {beg,cnt}

    const int BS = 256;

    // 1. setup: weights, zeroing, graph counts
    k_misc<<<MISC_BLOCKS, BS, 0, stream>>>(W1, WT1, W2, Wlin, b2, blin, w2l,
                                           (int*)gsum, bat, cntf);
    // 2. GEMM half A || pass-1 scatter into fixed bucket regions (391+391 blocks)
    k_gA_p1<<<GEMM_HALF + P1_BLOCKS, BS, 0, stream>>>(x, WT1, bufA, src, dst, bcur, pairs);
    // 3. GEMM half B || pass-2 bucket sort + rank-major meta + node meta
    k_gB_p2<<<GEMM_HALF + NCB, BS, 0, stream>>>(x, WT1, bufA, pairs, bcur, csr_src,
                                                dinv, meta, nm);
    // 4. layer-1 gather + fused projection to scalar z
    k_gather1<<<G1_BLOCKS, BS, 0, stream>>>(bufA, csr_src, dinv, b1, w2l, meta, z);
    // 5. layer-2 + pool over scalar z (node-order, LDS graph accumulation)
    k_g2<<<G2_BLOCKS, BS, 0, stream>>>(z, csr_src, nm, dinv, bat, gsum);
    // 6. final (trivial)
    k_final<<<(NGRAPHS + BS - 1) / BS, BS, 0, stream>>>(gsum, cntf, w2l + 128, out);
}